// Round 10
// baseline (340.159 us; speedup 1.0000x reference)
//
#include <hip/hip_runtime.h>

// MultiCellLSTM: B=4096 chains, H=64, T=512, 3 cell types by t%4 (0,2,1,2).
// R11: DUPLICATED-MFMA row-split -> 2 waves/SIMD with NO mid-step exchange.
// 512 thr / 8 waves / 256 blocks. Wave (w,e): w = h-slice 0..3, e = row-half.
// Both e-waves compute the IDENTICAL full gate tile (8 chained MFMAs + 4
// hoisted zx MFMAs; same ds_reads, LDS broadcasts). Wave e activates only
// D-rows {2e,2e+1} (2 cells/lane = 14 trans, halved) and writes its 2 h-cols
// (cvt_pk + ds_write_b32). cx partitioned per wave. Only coupling = the
// end-of-step barrier: R8's serializing mid-step exchange is absent; CU
// count stays 256 (R5's halving absent). Per-SIMD trans issue unchanged
// (28 = 448cy pipe floor) but two interleaved waves fill each other's
// dependency stalls (the ~500cy/step exposed latency at 1 wave/SIMD).
// Activation element indices are compile-time (template base) to avoid
// dynamic ext_vector indexing -> scratch (rule #20).
// Math per cell is bit-identical to R10 (same MFMA assoc, same activation).
// Carried from R10/R7: pre-packed x in LDS (xAf = bf16(x1)|bf16(x2)<<16,
// xBf = bf16(x3)), group-ahead lgkm-only prefetch; operand-swapped MFMA
// (D=W.hx^T); scale folded into weights (act via exp2/rcp, clamps at 60);
// bias as MFMA C-input; x-MFMA+bias hoist (neutral but shortens MFMA
// critical path); gate order {f,g,i,o}; ONE barrier/step.
// Stale x2/x3 at off-phase steps are masked by zero weight columns.

typedef __attribute__((ext_vector_type(8))) short short8v;
typedef __attribute__((ext_vector_type(4))) float float4v;
typedef __attribute__((ext_vector_type(2))) float float2v;
typedef __attribute__((ext_vector_type(4))) unsigned int uint4v;

template <int N> struct IC { static constexpr int value = N; };

#define AST 72    // shorts per A row: 64 hx + 8 pad; 16B-aligned frags
#define XSA 516   // dwords per xA row (512+4 pad)
#define XSB 129   // dwords per xB row (128+1 pad)

#if __has_builtin(__builtin_amdgcn_exp2f)
#define EXP2F(x) __builtin_amdgcn_exp2f(x)
#else
#define EXP2F(x) exp2f(x)
#endif
#if __has_builtin(__builtin_amdgcn_rcpf)
#define RCPF(x) __builtin_amdgcn_rcpf(x)
#else
#define RCPF(x) (1.0f / (x))
#endif

#define NL2E -1.4426950408889634f   // -log2(e)
#define NL2E2 -2.8853900817779268f  // -2*log2(e)

__device__ __forceinline__ short f2bf(float f) {
  union { float f; unsigned u; } v; v.f = f;
  unsigned r = v.u + 0x7FFFu + ((v.u >> 16) & 1u);  // RNE
  return (short)(r >> 16);
}
__device__ __forceinline__ float bf2f(short h) {
  union { float f; unsigned u; } v;
  v.u = ((unsigned)(unsigned short)h) << 16;
  return v.f;
}
// pack two f32 -> two bf16 (RNE) in one instr: lo | hi<<16
__device__ __forceinline__ unsigned cvt_pk_bf16(float lo, float hi) {
  unsigned r;
  asm("v_cvt_pk_bf16_f32 %0, %1, %2" : "=v"(r) : "v"(lo), "v"(hi));
  return r;
}
// act on pre-scaled y: sigmoid(x) = rcp(1+exp2(y)), y = x*NL2E
__device__ __forceinline__ float rcp1p(float y) {
  return RCPF(1.0f + EXP2F(y));
}
__device__ __forceinline__ float fsig(float x) { return rcp1p(x * NL2E); }

__global__ __launch_bounds__(512, 1) void mlstm_kernel(
    const float* __restrict__ x1, const float* __restrict__ x2,
    const float* __restrict__ x3,
    const float* __restrict__ Wi3, const float* __restrict__ Wh3,
    const float* __restrict__ bi3, const float* __restrict__ bh3,
    const float* __restrict__ Wi2, const float* __restrict__ Wh2,
    const float* __restrict__ bi2, const float* __restrict__ bh2,
    const float* __restrict__ Wi1, const float* __restrict__ Wh1,
    const float* __restrict__ bi1, const float* __restrict__ bh1,
    const float* __restrict__ Wout, const float* __restrict__ bout,
    float* __restrict__ out) {
  __shared__ __attribute__((aligned(16))) short Ab0[16 * AST];
  __shared__ __attribute__((aligned(16))) short Ab1[16 * AST];
  __shared__ __attribute__((aligned(16))) unsigned xAf[16 * XSA];
  __shared__ __attribute__((aligned(16))) unsigned xBf[16 * XSB];

  const int tid = threadIdx.x;   // 0..511
  const int w = (tid >> 6) & 3;  // h-col slice 0..3
  const int e = tid >> 8;        // row-half 0..1 (activation split)
  const int lane = tid & 63;
  const int q = lane >> 4;
  const int c = lane & 15;
  const int R0 = blockIdx.x << 4;

  // ---- preload x into LDS, pre-packed as a2 dwords ----
  for (int idx = tid; idx < 16 * 256; idx += 512) {
    int m = idx >> 8, tp = idx & 255;
    float2v v1 = *(const float2v*)(x1 + (size_t)(R0 + m) * 512 + 2 * tp);
    float v2 = x2[(size_t)(R0 + m) * 256 + tp];
    xAf[m * XSA + 2 * tp] = cvt_pk_bf16(v1[0], v2);
    xAf[m * XSA + 2 * tp + 1] = cvt_pk_bf16(v1[1], v2);
  }
  for (int idx = tid; idx < 16 * 128; idx += 512) {
    int m = idx >> 7, tt = idx & 127;
    xBf[m * XSB + tt] = cvt_pk_bf16(x3[(size_t)(R0 + m) * 128 + tt], 0.0f);
  }
  // ---- A buffers: hx(t=0) = 0 ----
  for (int idx = tid; idx < 16 * AST; idx += 512) {
    Ab0[idx] = 0;
    Ab1[idx] = 0;
  }

  // ---- pack scaled weight fragments (per wave: tiles g=0..3; e-pair waves
  //      pack identical copies) ----
  short8v whs[3][4][2];
  short8v wix[3][4];
  float4v bias4[3][4];
  {
    const float* WhA[3] = {Wh3, Wh2, Wh1};
    const float* WiA[3] = {Wi3, Wi2, Wi1};
    const float* biA[3] = {bi3, bi2, bi1};
    const float* bhA[3] = {bh3, bh2, bh1};
    const int wdt[3] = {3, 2, 1};
#pragma unroll
    for (int ty = 0; ty < 3; ++ty) {
#pragma unroll
      for (int g = 0; g < 4; ++g) {
        const float sg = (g == 2) ? NL2E2 : NL2E;
        const int n = g * 64 + 16 * w + c;
#pragma unroll
        for (int kf = 0; kf < 2; ++kf) {
          short8v v;
#pragma unroll
          for (int j = 0; j < 8; ++j)
            v[j] = f2bf(sg * WhA[ty][n * 64 + kf * 32 + q * 8 + j]);
          whs[ty][g][kf] = v;
        }
        short8v v2 = {0, 0, 0, 0, 0, 0, 0, 0};
        if (q == 0) {
#pragma unroll
          for (int j = 0; j < 3; ++j)
            if (j < wdt[ty]) v2[j] = f2bf(sg * WiA[ty][n * wdt[ty] + j]);
        }
        wix[ty][g] = v2;
        float4v bv;
#pragma unroll
        for (int r = 0; r < 4; ++r) {
          const int nd = g * 64 + 16 * w + 4 * q + r;  // D-row = gate col
          bv[r] = sg * (biA[ty][nd] + bhA[ty][nd]);
        }
        bias4[ty][g] = bv;
      }
    }
  }

  // addressing
  const int afo = c * AST + q * 8;          // hx frag: n=c(row), k=q*8+j
  const int hwo = c * AST + 16 * w + 4 * q; // h cols 16w+4q+r; this wave
                                            // writes r = 2e, 2e+1 (b32)
  const int xao = c * XSA;
  const int xbo = c * XSB;

  __syncthreads();

  float cx2[2] = {0.f, 0.f};  // cell state: row c, h-cols 16w+4q+2e+{0,1}

  // zx[g] = bias + x-part of gates, computed ONE STEP AHEAD (ping-pong A/B)
  float4v zxA[4], zxB[4];

  // gate completion order: f(1), g(2) feed the activation-chain head;
  // i(0) mid; o(3) is needed only at the end.
  const int GORD[4] = {1, 2, 0, 3};

  auto stepf = [&](auto tyc, auto tync, unsigned dSn, unsigned dx3n,
                   const short* rbuf, short* wbuf, float4v (&zin)[4],
                   float4v (&zout)[4]) {
    constexpr int TY = decltype(tyc)::value;
    constexpr int TYN = decltype(tync)::value;
    short8v a0 = *(const short8v*)(rbuf + afo);
    short8v a1 = *(const short8v*)(rbuf + afo + 32);

    float4v acc[4];
#pragma unroll
    for (int gi = 0; gi < 4; ++gi) {
      const int g = GORD[gi];
      float4v z =
          __builtin_amdgcn_mfma_f32_16x16x32_bf16(whs[TY][g][0], a0, zin[g], 0, 0, 0);
      acc[g] =
          __builtin_amdgcn_mfma_f32_16x16x32_bf16(whs[TY][g][1], a1, z, 0, 0, 0);
    }

    // hoisted x-part for NEXT step (register operands; MFMA pipe idle
    // during activation). Same association as R7 -> bit-identical.
    uint4v aun = {dSn, dx3n, 0u, 0u};
    short8v a2n = __builtin_bit_cast(short8v, aun);
#pragma unroll
    for (int g = 0; g < 4; ++g)
      zout[g] = __builtin_amdgcn_mfma_f32_16x16x32_bf16(wix[TYN][g], a2n,
                                                        bias4[TYN][g], 0, 0, 0);

    // activation: this wave's 2 rows only (B0 = 2e, compile-time via
    // template dispatch -> static vector indices, no scratch).
    auto act2 = [&](auto baseC) {
      constexpr int B0 = decltype(baseC)::value;
      float h2[2];
#pragma unroll
      for (int u = 0; u < 2; ++u) {
        const int r = B0 + u;
        float e0 = EXP2F(acc[0][r]);
        float e1 = EXP2F(acc[1][r]);
        float e2 = EXP2F(__builtin_fminf(acc[2][r], 60.0f));
        float e3 = EXP2F(acc[3][r]);
        float a = 1.0f + e0, b = 1.0f + e1, g2 = 1.0f + e2;
        float ag = a * g2;
        float Rr = RCPF(ag * b);  // one rcp covers sig(f), sig(i)*tanh(g)
        float ncx = __builtin_fmaf(cx2[u], ag, (1.0f - e2) * b) * Rr;
        cx2[u] = ncx;
        // sig(o)*tanh(ncx) = (1-e4)/((1+e3)(1+e4)); clamp keeps exact
        // tanh->-1 saturation limit instead of inf*0 = NaN
        float e4 = EXP2F(__builtin_fminf(ncx * NL2E2, 60.0f));
        h2[u] = (1.0f - e4) * RCPF((1.0f + e3) * (1.0f + e4));
      }
      *(unsigned*)(wbuf + hwo + B0) = cvt_pk_bf16(h2[0], h2[1]);
    };
    if (e == 0) act2(IC<0>{});
    else       act2(IC<2>{});
    __syncthreads();
  };

  // x dwords for group t4=0
  uint4v xd = *(const uint4v*)(xAf + xao);
  unsigned xw = xBf[xbo];

  // prologue: zx for t=0 (type 0)
  {
    uint4v au = {xd[0], xw, 0u, 0u};
    short8v a2 = __builtin_bit_cast(short8v, au);
#pragma unroll
    for (int g = 0; g < 4; ++g)
      zxA[g] = __builtin_amdgcn_mfma_f32_16x16x32_bf16(wix[0][g], a2,
                                                       bias4[0][g], 0, 0, 0);
  }

  // t%4 -> type: 0->0, 1->2, 2->1, 3->2; each step also builds next step's zx
  for (int t4 = 0; t4 < 512; t4 += 4) {
    stepf(IC<0>{}, IC<2>{}, xd[1], xw, Ab0, Ab1, zxA, zxB);
    // prefetch next group's x from LDS (clamped on last iter; unused)
    int tp = (t4 + 4 > 508) ? 508 : (t4 + 4);
    uint4v xdn = *(const uint4v*)(xAf + xao + tp);
    unsigned xwn = xBf[xbo + (tp >> 2)];
    stepf(IC<2>{}, IC<1>{}, xd[2], xw, Ab1, Ab0, zxB, zxA);
    stepf(IC<1>{}, IC<2>{}, xd[3], xw, Ab0, Ab1, zxA, zxB);
    stepf(IC<2>{}, IC<0>{}, xdn[0], xwn, Ab1, Ab0, zxB, zxA);
    xd = xdn;
    xw = xwn;
  }
  // final hx (after 512 steps) is in Ab0

  if (tid < 16) {
    float s = bout[0];
    const short* hr = Ab0 + tid * AST;
#pragma unroll
    for (int k = 0; k < 64; ++k)
      s = __builtin_fmaf(bf2f(hr[k]), Wout[k], s);
    out[R0 + tid] = fsig(s);
  }
}

extern "C" void kernel_launch(void* const* d_in, const int* in_sizes, int n_in,
                              void* d_out, int out_size, void* d_ws,
                              size_t ws_size, hipStream_t stream) {
  const float* x1 = (const float*)d_in[0];
  const float* x2 = (const float*)d_in[1];
  const float* x3 = (const float*)d_in[2];
  const float* Wi3 = (const float*)d_in[3];
  const float* Wh3 = (const float*)d_in[4];
  const float* bi3 = (const float*)d_in[5];
  const float* bh3 = (const float*)d_in[6];
  const float* Wi2 = (const float*)d_in[7];
  const float* Wh2 = (const float*)d_in[8];
  const float* bi2 = (const float*)d_in[9];
  const float* bh2 = (const float*)d_in[10];
  const float* Wi1 = (const float*)d_in[11];
  const float* Wh1 = (const float*)d_in[12];
  const float* bi1 = (const float*)d_in[13];
  const float* bh1 = (const float*)d_in[14];
  const float* Wout = (const float*)d_in[15];
  const float* bout = (const float*)d_in[16];
  float* out = (float*)d_out;

  hipLaunchKernelGGL(mlstm_kernel, dim3(256), dim3(512), 0, stream,
                     x1, x2, x3, Wi3, Wh3, bi3, bh3, Wi2, Wh2, bi2, bh2,
                     Wi1, Wh1, bi1, bh1, Wout, bout, out);
}

// Round 11
// 332.561 us; speedup vs baseline: 1.0228x; 1.0228x over previous
//
#include <hip/hip_runtime.h>

// MultiCellLSTM: B=4096 chains, H=64, T=512, 3 cell types by t%4 (0,2,1,2).
// R12: R11's duplicated-MFMA row-split, REGISTER-DIETED to fit the 2-wave
// budget. R11 spilled (274 regs > 256 @ 2 waves/SIMD -> 128-cap + 113MB
// scratch); R8 (210 regs, same 512-thr shape) did NOT spill -> the design
// is viable iff total <= 256. Diet vs R11 (-54):
//  - zx hoist dropped (R10 proved neutral): -16 AGPR + machinery.
//  - bias4 C-input dropped -> C=0, bias added in activation for THIS wave's
//    2 rows only: bias2[3][4] float2 = 24 regs (was 48), +8 v_add/step.
// Structure: 512 thr / 8 waves / 256 blocks (16 rows). Wave (w,e): both
// e-waves compute the IDENTICAL full gate tile (12 MFMAs, same ds_reads,
// LDS broadcast); wave e activates only D-rows {2e,2e+1} (2 cells/lane ->
// 14 trans) and writes its 2 h-cols (cvt_pk + ds_write_b32). cx per wave.
// Only coupling = end-of-step barrier (R8's mid-step exchange absent; CU
// count stays 256). Per-SIMD: 2 waves x ~350cy issue interleave to fill
// the ~500cy dependency latency R7 could not hide at 1 wave/SIMD.
// Carried from R7: pre-packed x in LDS (xAf = bf16(x1)|bf16(x2)<<16, xBf =
// bf16(x3)), group-ahead lgkm-only prefetch; operand-swapped MFMA
// (D=W.hx^T); scale folded into weights (act via exp2/rcp, clamps at 60);
// ONE barrier/step. Stale x2/x3 masked by zero weight columns.

typedef __attribute__((ext_vector_type(8))) short short8v;
typedef __attribute__((ext_vector_type(4))) float float4v;
typedef __attribute__((ext_vector_type(2))) float float2v;
typedef __attribute__((ext_vector_type(4))) unsigned int uint4v;

template <int N> struct IC { static constexpr int value = N; };

#define AST 72    // shorts per A row: 64 hx + 8 pad; 16B-aligned frags
#define XSA 516   // dwords per xA row (512+4 pad)
#define XSB 129   // dwords per xB row (128+1 pad)

#if __has_builtin(__builtin_amdgcn_exp2f)
#define EXP2F(x) __builtin_amdgcn_exp2f(x)
#else
#define EXP2F(x) exp2f(x)
#endif
#if __has_builtin(__builtin_amdgcn_rcpf)
#define RCPF(x) __builtin_amdgcn_rcpf(x)
#else
#define RCPF(x) (1.0f / (x))
#endif

#define NL2E -1.4426950408889634f   // -log2(e)
#define NL2E2 -2.8853900817779268f  // -2*log2(e)

__device__ __forceinline__ short f2bf(float f) {
  union { float f; unsigned u; } v; v.f = f;
  unsigned r = v.u + 0x7FFFu + ((v.u >> 16) & 1u);  // RNE
  return (short)(r >> 16);
}
__device__ __forceinline__ float bf2f(short h) {
  union { float f; unsigned u; } v;
  v.u = ((unsigned)(unsigned short)h) << 16;
  return v.f;
}
// pack two f32 -> two bf16 (RNE) in one instr: lo | hi<<16
__device__ __forceinline__ unsigned cvt_pk_bf16(float lo, float hi) {
  unsigned r;
  asm("v_cvt_pk_bf16_f32 %0, %1, %2" : "=v"(r) : "v"(lo), "v"(hi));
  return r;
}
// act on pre-scaled y: sigmoid(x) = rcp(1+exp2(y)), y = x*NL2E
__device__ __forceinline__ float rcp1p(float y) {
  return RCPF(1.0f + EXP2F(y));
}
__device__ __forceinline__ float fsig(float x) { return rcp1p(x * NL2E); }

__global__ __launch_bounds__(512, 2) void mlstm_kernel(
    const float* __restrict__ x1, const float* __restrict__ x2,
    const float* __restrict__ x3,
    const float* __restrict__ Wi3, const float* __restrict__ Wh3,
    const float* __restrict__ bi3, const float* __restrict__ bh3,
    const float* __restrict__ Wi2, const float* __restrict__ Wh2,
    const float* __restrict__ bi2, const float* __restrict__ bh2,
    const float* __restrict__ Wi1, const float* __restrict__ Wh1,
    const float* __restrict__ bi1, const float* __restrict__ bh1,
    const float* __restrict__ Wout, const float* __restrict__ bout,
    float* __restrict__ out) {
  __shared__ __attribute__((aligned(16))) short Ab0[16 * AST];
  __shared__ __attribute__((aligned(16))) short Ab1[16 * AST];
  __shared__ __attribute__((aligned(16))) unsigned xAf[16 * XSA];
  __shared__ __attribute__((aligned(16))) unsigned xBf[16 * XSB];

  const int tid = threadIdx.x;   // 0..511
  const int w = (tid >> 6) & 3;  // h-col slice 0..3
  const int e = tid >> 8;        // row-half 0..1 (activation split)
  const int lane = tid & 63;
  const int q = lane >> 4;
  const int c = lane & 15;
  const int R0 = blockIdx.x << 4;

  // ---- preload x into LDS, pre-packed as a2 dwords ----
  for (int idx = tid; idx < 16 * 256; idx += 512) {
    int m = idx >> 8, tp = idx & 255;
    float2v v1 = *(const float2v*)(x1 + (size_t)(R0 + m) * 512 + 2 * tp);
    float v2 = x2[(size_t)(R0 + m) * 256 + tp];
    xAf[m * XSA + 2 * tp] = cvt_pk_bf16(v1[0], v2);
    xAf[m * XSA + 2 * tp + 1] = cvt_pk_bf16(v1[1], v2);
  }
  for (int idx = tid; idx < 16 * 128; idx += 512) {
    int m = idx >> 7, tt = idx & 127;
    xBf[m * XSB + tt] = cvt_pk_bf16(x3[(size_t)(R0 + m) * 128 + tt], 0.0f);
  }
  // ---- A buffers: hx(t=0) = 0 ----
  for (int idx = tid; idx < 16 * AST; idx += 512) {
    Ab0[idx] = 0;
    Ab1[idx] = 0;
  }

  // ---- pack scaled weight fragments (per wave: tiles g=0..3; e-pair waves
  //      hold identical whs/wix copies; bias only for own 2 rows) ----
  short8v whs[3][4][2];
  short8v wix[3][4];
  float2v bias2[3][4];  // elem u = s_g*(bi+bh)[g*64+16w+4q+2e+u]
  {
    const float* WhA[3] = {Wh3, Wh2, Wh1};
    const float* WiA[3] = {Wi3, Wi2, Wi1};
    const float* biA[3] = {bi3, bi2, bi1};
    const float* bhA[3] = {bh3, bh2, bh1};
    const int wdt[3] = {3, 2, 1};
#pragma unroll
    for (int ty = 0; ty < 3; ++ty) {
#pragma unroll
      for (int g = 0; g < 4; ++g) {
        const float sg = (g == 2) ? NL2E2 : NL2E;
        const int n = g * 64 + 16 * w + c;
#pragma unroll
        for (int kf = 0; kf < 2; ++kf) {
          short8v v;
#pragma unroll
          for (int j = 0; j < 8; ++j)
            v[j] = f2bf(sg * WhA[ty][n * 64 + kf * 32 + q * 8 + j]);
          whs[ty][g][kf] = v;
        }
        short8v v2 = {0, 0, 0, 0, 0, 0, 0, 0};
        if (q == 0) {
#pragma unroll
          for (int j = 0; j < 3; ++j)
            if (j < wdt[ty]) v2[j] = f2bf(sg * WiA[ty][n * wdt[ty] + j]);
        }
        wix[ty][g] = v2;
        float2v bv;
#pragma unroll
        for (int u = 0; u < 2; ++u) {
          const int nd = g * 64 + 16 * w + 4 * q + 2 * e + u;
          bv[u] = sg * (biA[ty][nd] + bhA[ty][nd]);
        }
        bias2[ty][g] = bv;
      }
    }
  }

  // addressing
  const int afo = c * AST + q * 8;          // hx frag: n=c(row), k=q*8+j
  const int hwo = c * AST + 16 * w + 4 * q + 2 * e;  // my 2 h-cols (b32)
  const int xao = c * XSA;
  const int xbo = c * XSB;

  __syncthreads();

  float cx2[2] = {0.f, 0.f};  // cell state: row c, h-cols 16w+4q+2e+{0,1}
  const float4v ZZ = {0.f, 0.f, 0.f, 0.f};

  auto stepf = [&](auto tyc, unsigned dS, unsigned dx3, const short* rbuf,
                   short* wbuf) {
    constexpr int TY = decltype(tyc)::value;
    // x(t) B-frag: k0=x1, k1=x2, k2=x3, rest 0; stale x2/x3 (and q>0
    // lanes) are multiplied by zero weight columns.
    uint4v au = {dS, dx3, 0u, 0u};
    short8v a2 = __builtin_bit_cast(short8v, au);
    short8v a0 = *(const short8v*)(rbuf + afo);
    short8v a1 = *(const short8v*)(rbuf + afo + 32);

    float4v acc[4];
#pragma unroll
    for (int g = 0; g < 4; ++g) {
      // x-MFMA first (register operands) overlaps the a0/a1 ds_read latency
      float4v z = __builtin_amdgcn_mfma_f32_16x16x32_bf16(wix[TY][g], a2, ZZ, 0, 0, 0);
      z = __builtin_amdgcn_mfma_f32_16x16x32_bf16(whs[TY][g][0], a0, z, 0, 0, 0);
      acc[g] = __builtin_amdgcn_mfma_f32_16x16x32_bf16(whs[TY][g][1], a1, z, 0, 0, 0);
    }

    // activation: this wave's 2 rows only (B0 = 2e compile-time -> static
    // vector indices, no scratch). Bias added here (was MFMA C-input).
    auto act2 = [&](auto baseC) {
      constexpr int B0 = decltype(baseC)::value;
      float h2[2];
#pragma unroll
      for (int u = 0; u < 2; ++u) {
        float G0 = acc[0][B0 + u] + bias2[TY][0][u];
        float G1 = acc[1][B0 + u] + bias2[TY][1][u];
        float G2 = acc[2][B0 + u] + bias2[TY][2][u];
        float G3 = acc[3][B0 + u] + bias2[TY][3][u];
        float e0 = EXP2F(G0);
        float e1 = EXP2F(G1);
        float e2 = EXP2F(__builtin_fminf(G2, 60.0f));
        float e3 = EXP2F(G3);
        float a = 1.0f + e0, b = 1.0f + e1, g2 = 1.0f + e2;
        float ag = a * g2;
        float Rr = RCPF(ag * b);  // one rcp covers sig(f), sig(i)*tanh(g)
        float ncx = __builtin_fmaf(cx2[u], ag, (1.0f - e2) * b) * Rr;
        cx2[u] = ncx;
        // sig(o)*tanh(ncx) = (1-e4)/((1+e3)(1+e4)); clamp keeps exact
        // tanh->-1 saturation limit instead of inf*0 = NaN
        float e4 = EXP2F(__builtin_fminf(ncx * NL2E2, 60.0f));
        h2[u] = (1.0f - e4) * RCPF((1.0f + e3) * (1.0f + e4));
      }
      *(unsigned*)(wbuf + hwo) = cvt_pk_bf16(h2[0], h2[1]);
    };
    if (e == 0) act2(IC<0>{});
    else       act2(IC<2>{});
    __syncthreads();
  };

  // x dwords for group t4=0
  uint4v xd = *(const uint4v*)(xAf + xao);
  unsigned xw = xBf[xbo];

  // t%4 -> type: 0->0, 1->2, 2->1, 3->2
  for (int t4 = 0; t4 < 512; t4 += 4) {
    stepf(IC<0>{}, xd[0], xw, Ab0, Ab1);
    // prefetch next group's x from LDS (clamped on last iter; unused).
    // lgkm-only; fully hidden by one step even with barrier drains.
    int tp = (t4 + 4 > 508) ? 508 : (t4 + 4);
    uint4v xdn = *(const uint4v*)(xAf + xao + tp);
    unsigned xwn = xBf[xbo + (tp >> 2)];
    stepf(IC<2>{}, xd[1], xw, Ab1, Ab0);
    stepf(IC<1>{}, xd[2], xw, Ab0, Ab1);
    stepf(IC<2>{}, xd[3], xw, Ab1, Ab0);
    xd = xdn;
    xw = xwn;
  }
  // final hx (after 512 steps) is in Ab0

  if (tid < 16) {
    float s = bout[0];
    const short* hr = Ab0 + tid * AST;
#pragma unroll
    for (int k = 0; k < 64; ++k)
      s = __builtin_fmaf(bf2f(hr[k]), Wout[k], s);
    out[R0 + tid] = fsig(s);
  }
}

extern "C" void kernel_launch(void* const* d_in, const int* in_sizes, int n_in,
                              void* d_out, int out_size, void* d_ws,
                              size_t ws_size, hipStream_t stream) {
  const float* x1 = (const float*)d_in[0];
  const float* x2 = (const float*)d_in[1];
  const float* x3 = (const float*)d_in[2];
  const float* Wi3 = (const float*)d_in[3];
  const float* Wh3 = (const float*)d_in[4];
  const float* bi3 = (const float*)d_in[5];
  const float* bh3 = (const float*)d_in[6];
  const float* Wi2 = (const float*)d_in[7];
  const float* Wh2 = (const float*)d_in[8];
  const float* bi2 = (const float*)d_in[9];
  const float* bh2 = (const float*)d_in[10];
  const float* Wi1 = (const float*)d_in[11];
  const float* Wh1 = (const float*)d_in[12];
  const float* bi1 = (const float*)d_in[13];
  const float* bh1 = (const float*)d_in[14];
  const float* Wout = (const float*)d_in[15];
  const float* bout = (const float*)d_in[16];
  float* out = (float*)d_out;

  hipLaunchKernelGGL(mlstm_kernel, dim3(256), dim3(512), 0, stream,
                     x1, x2, x3, Wi3, Wh3, bi3, bh3, Wi2, Wh2, bi2, bh2,
                     Wi1, Wh1, bi1, bh1, Wout, bout, out);
}

// Round 12
// 328.549 us; speedup vs baseline: 1.0353x; 1.0122x over previous
//
#include <hip/hip_runtime.h>

// MultiCellLSTM: B=4096 chains, H=64, T=512, 3 cell types by t%4 (0,2,1,2).
// R13: R12 with the launch-bounds bug FIXED. R12 accidentally used
// __launch_bounds__(512,2) (= 2 blocks/CU = 4 waves/SIMD = 128-reg total
// cap) -> guaranteed spill (FETCH 28.5MB/WRITE 41MB), the exact R5 mistake.
// With (512,1): 1 block/CU, 2 waves/SIMD, 256 regs/wave total (unified
// VGPR+AGPR file; R8's ~210-reg kernel fit this budget spill-free).
// R12's diet footprint ~214 regs: whs 96 + wix 48 + bias2 24 + acc 16 +
// misc ~30. Even WITH spill R12 ran 281us @ MfmaUtil 31% / Occ 22.6% --
// the duplicated-MFMA 2-wave mechanism works; this run removes the spill.
// Structure (R12): 512 thr / 8 waves / 256 blocks (16 rows). Wave (w,e):
// both e-waves compute the IDENTICAL full gate tile (12 MFMAs, same
// ds_reads, LDS broadcast); wave e activates only D-rows {2e,2e+1}
// (2 cells/lane -> 14 trans) and writes its 2 h-cols (cvt_pk +
// ds_write_b32). cx per wave. Only coupling = end-of-step barrier (R8's
// serializing mid-step exchange absent; CU count stays 256). bias added in
// activation (bias2[3][4] float2, 24 regs) instead of MFMA C-input.
// Carried from R7: pre-packed x in LDS (xAf = bf16(x1)|bf16(x2)<<16, xBf =
// bf16(x3)), group-ahead lgkm-only prefetch; operand-swapped MFMA
// (D=W.hx^T); scale folded into weights (act via exp2/rcp, clamps at 60);
// ONE barrier/step. Stale x2/x3 masked by zero weight columns.

typedef __attribute__((ext_vector_type(8))) short short8v;
typedef __attribute__((ext_vector_type(4))) float float4v;
typedef __attribute__((ext_vector_type(2))) float float2v;
typedef __attribute__((ext_vector_type(4))) unsigned int uint4v;

template <int N> struct IC { static constexpr int value = N; };

#define AST 72    // shorts per A row: 64 hx + 8 pad; 16B-aligned frags
#define XSA 516   // dwords per xA row (512+4 pad)
#define XSB 129   // dwords per xB row (128+1 pad)

#if __has_builtin(__builtin_amdgcn_exp2f)
#define EXP2F(x) __builtin_amdgcn_exp2f(x)
#else
#define EXP2F(x) exp2f(x)
#endif
#if __has_builtin(__builtin_amdgcn_rcpf)
#define RCPF(x) __builtin_amdgcn_rcpf(x)
#else
#define RCPF(x) (1.0f / (x))
#endif

#define NL2E -1.4426950408889634f   // -log2(e)
#define NL2E2 -2.8853900817779268f  // -2*log2(e)

__device__ __forceinline__ short f2bf(float f) {
  union { float f; unsigned u; } v; v.f = f;
  unsigned r = v.u + 0x7FFFu + ((v.u >> 16) & 1u);  // RNE
  return (short)(r >> 16);
}
__device__ __forceinline__ float bf2f(short h) {
  union { float f; unsigned u; } v;
  v.u = ((unsigned)(unsigned short)h) << 16;
  return v.f;
}
// pack two f32 -> two bf16 (RNE) in one instr: lo | hi<<16
__device__ __forceinline__ unsigned cvt_pk_bf16(float lo, float hi) {
  unsigned r;
  asm("v_cvt_pk_bf16_f32 %0, %1, %2" : "=v"(r) : "v"(lo), "v"(hi));
  return r;
}
// act on pre-scaled y: sigmoid(x) = rcp(1+exp2(y)), y = x*NL2E
__device__ __forceinline__ float rcp1p(float y) {
  return RCPF(1.0f + EXP2F(y));
}
__device__ __forceinline__ float fsig(float x) { return rcp1p(x * NL2E); }

__global__ __launch_bounds__(512, 1) void mlstm_kernel(
    const float* __restrict__ x1, const float* __restrict__ x2,
    const float* __restrict__ x3,
    const float* __restrict__ Wi3, const float* __restrict__ Wh3,
    const float* __restrict__ bi3, const float* __restrict__ bh3,
    const float* __restrict__ Wi2, const float* __restrict__ Wh2,
    const float* __restrict__ bi2, const float* __restrict__ bh2,
    const float* __restrict__ Wi1, const float* __restrict__ Wh1,
    const float* __restrict__ bi1, const float* __restrict__ bh1,
    const float* __restrict__ Wout, const float* __restrict__ bout,
    float* __restrict__ out) {
  __shared__ __attribute__((aligned(16))) short Ab0[16 * AST];
  __shared__ __attribute__((aligned(16))) short Ab1[16 * AST];
  __shared__ __attribute__((aligned(16))) unsigned xAf[16 * XSA];
  __shared__ __attribute__((aligned(16))) unsigned xBf[16 * XSB];

  const int tid = threadIdx.x;   // 0..511
  const int w = (tid >> 6) & 3;  // h-col slice 0..3
  const int e = tid >> 8;        // row-half 0..1 (activation split)
  const int lane = tid & 63;
  const int q = lane >> 4;
  const int c = lane & 15;
  const int R0 = blockIdx.x << 4;

  // ---- preload x into LDS, pre-packed as a2 dwords ----
  for (int idx = tid; idx < 16 * 256; idx += 512) {
    int m = idx >> 8, tp = idx & 255;
    float2v v1 = *(const float2v*)(x1 + (size_t)(R0 + m) * 512 + 2 * tp);
    float v2 = x2[(size_t)(R0 + m) * 256 + tp];
    xAf[m * XSA + 2 * tp] = cvt_pk_bf16(v1[0], v2);
    xAf[m * XSA + 2 * tp + 1] = cvt_pk_bf16(v1[1], v2);
  }
  for (int idx = tid; idx < 16 * 128; idx += 512) {
    int m = idx >> 7, tt = idx & 127;
    xBf[m * XSB + tt] = cvt_pk_bf16(x3[(size_t)(R0 + m) * 128 + tt], 0.0f);
  }
  // ---- A buffers: hx(t=0) = 0 ----
  for (int idx = tid; idx < 16 * AST; idx += 512) {
    Ab0[idx] = 0;
    Ab1[idx] = 0;
  }

  // ---- pack scaled weight fragments (per wave: tiles g=0..3; e-pair waves
  //      hold identical whs/wix copies; bias only for own 2 rows) ----
  short8v whs[3][4][2];
  short8v wix[3][4];
  float2v bias2[3][4];  // elem u = s_g*(bi+bh)[g*64+16w+4q+2e+u]
  {
    const float* WhA[3] = {Wh3, Wh2, Wh1};
    const float* WiA[3] = {Wi3, Wi2, Wi1};
    const float* biA[3] = {bi3, bi2, bi1};
    const float* bhA[3] = {bh3, bh2, bh1};
    const int wdt[3] = {3, 2, 1};
#pragma unroll
    for (int ty = 0; ty < 3; ++ty) {
#pragma unroll
      for (int g = 0; g < 4; ++g) {
        const float sg = (g == 2) ? NL2E2 : NL2E;
        const int n = g * 64 + 16 * w + c;
#pragma unroll
        for (int kf = 0; kf < 2; ++kf) {
          short8v v;
#pragma unroll
          for (int j = 0; j < 8; ++j)
            v[j] = f2bf(sg * WhA[ty][n * 64 + kf * 32 + q * 8 + j]);
          whs[ty][g][kf] = v;
        }
        short8v v2 = {0, 0, 0, 0, 0, 0, 0, 0};
        if (q == 0) {
#pragma unroll
          for (int j = 0; j < 3; ++j)
            if (j < wdt[ty]) v2[j] = f2bf(sg * WiA[ty][n * wdt[ty] + j]);
        }
        wix[ty][g] = v2;
        float2v bv;
#pragma unroll
        for (int u = 0; u < 2; ++u) {
          const int nd = g * 64 + 16 * w + 4 * q + 2 * e + u;
          bv[u] = sg * (biA[ty][nd] + bhA[ty][nd]);
        }
        bias2[ty][g] = bv;
      }
    }
  }

  // addressing
  const int afo = c * AST + q * 8;          // hx frag: n=c(row), k=q*8+j
  const int hwo = c * AST + 16 * w + 4 * q + 2 * e;  // my 2 h-cols (b32)
  const int xao = c * XSA;
  const int xbo = c * XSB;

  __syncthreads();

  float cx2[2] = {0.f, 0.f};  // cell state: row c, h-cols 16w+4q+2e+{0,1}
  const float4v ZZ = {0.f, 0.f, 0.f, 0.f};

  auto stepf = [&](auto tyc, unsigned dS, unsigned dx3, const short* rbuf,
                   short* wbuf) {
    constexpr int TY = decltype(tyc)::value;
    // x(t) B-frag: k0=x1, k1=x2, k2=x3, rest 0; stale x2/x3 (and q>0
    // lanes) are multiplied by zero weight columns.
    uint4v au = {dS, dx3, 0u, 0u};
    short8v a2 = __builtin_bit_cast(short8v, au);
    short8v a0 = *(const short8v*)(rbuf + afo);
    short8v a1 = *(const short8v*)(rbuf + afo + 32);

    float4v acc[4];
#pragma unroll
    for (int g = 0; g < 4; ++g) {
      // x-MFMA first (register operands) overlaps the a0/a1 ds_read latency
      float4v z = __builtin_amdgcn_mfma_f32_16x16x32_bf16(wix[TY][g], a2, ZZ, 0, 0, 0);
      z = __builtin_amdgcn_mfma_f32_16x16x32_bf16(whs[TY][g][0], a0, z, 0, 0, 0);
      acc[g] = __builtin_amdgcn_mfma_f32_16x16x32_bf16(whs[TY][g][1], a1, z, 0, 0, 0);
    }

    // activation: this wave's 2 rows only (B0 = 2e compile-time -> static
    // vector indices, no scratch). Bias added here (was MFMA C-input).
    auto act2 = [&](auto baseC) {
      constexpr int B0 = decltype(baseC)::value;
      float h2[2];
#pragma unroll
      for (int u = 0; u < 2; ++u) {
        float G0 = acc[0][B0 + u] + bias2[TY][0][u];
        float G1 = acc[1][B0 + u] + bias2[TY][1][u];
        float G2 = acc[2][B0 + u] + bias2[TY][2][u];
        float G3 = acc[3][B0 + u] + bias2[TY][3][u];
        float e0 = EXP2F(G0);
        float e1 = EXP2F(G1);
        float e2 = EXP2F(__builtin_fminf(G2, 60.0f));
        float e3 = EXP2F(G3);
        float a = 1.0f + e0, b = 1.0f + e1, g2 = 1.0f + e2;
        float ag = a * g2;
        float Rr = RCPF(ag * b);  // one rcp covers sig(f), sig(i)*tanh(g)
        float ncx = __builtin_fmaf(cx2[u], ag, (1.0f - e2) * b) * Rr;
        cx2[u] = ncx;
        // sig(o)*tanh(ncx) = (1-e4)/((1+e3)(1+e4)); clamp keeps exact
        // tanh->-1 saturation limit instead of inf*0 = NaN
        float e4 = EXP2F(__builtin_fminf(ncx * NL2E2, 60.0f));
        h2[u] = (1.0f - e4) * RCPF((1.0f + e3) * (1.0f + e4));
      }
      *(unsigned*)(wbuf + hwo) = cvt_pk_bf16(h2[0], h2[1]);
    };
    if (e == 0) act2(IC<0>{});
    else       act2(IC<2>{});
    __syncthreads();
  };

  // x dwords for group t4=0
  uint4v xd = *(const uint4v*)(xAf + xao);
  unsigned xw = xBf[xbo];

  // t%4 -> type: 0->0, 1->2, 2->1, 3->2
  for (int t4 = 0; t4 < 512; t4 += 4) {
    stepf(IC<0>{}, xd[0], xw, Ab0, Ab1);
    // prefetch next group's x from LDS (clamped on last iter; unused).
    // lgkm-only; fully hidden by one step even with barrier drains.
    int tp = (t4 + 4 > 508) ? 508 : (t4 + 4);
    uint4v xdn = *(const uint4v*)(xAf + xao + tp);
    unsigned xwn = xBf[xbo + (tp >> 2)];
    stepf(IC<2>{}, xd[1], xw, Ab1, Ab0);
    stepf(IC<1>{}, xd[2], xw, Ab0, Ab1);
    stepf(IC<2>{}, xd[3], xw, Ab1, Ab0);
    xd = xdn;
    xw = xwn;
  }
  // final hx (after 512 steps) is in Ab0

  if (tid < 16) {
    float s = bout[0];
    const short* hr = Ab0 + tid * AST;
#pragma unroll
    for (int k = 0; k < 64; ++k)
      s = __builtin_fmaf(bf2f(hr[k]), Wout[k], s);
    out[R0 + tid] = fsig(s);
  }
}

extern "C" void kernel_launch(void* const* d_in, const int* in_sizes, int n_in,
                              void* d_out, int out_size, void* d_ws,
                              size_t ws_size, hipStream_t stream) {
  const float* x1 = (const float*)d_in[0];
  const float* x2 = (const float*)d_in[1];
  const float* x3 = (const float*)d_in[2];
  const float* Wi3 = (const float*)d_in[3];
  const float* Wh3 = (const float*)d_in[4];
  const float* bi3 = (const float*)d_in[5];
  const float* bh3 = (const float*)d_in[6];
  const float* Wi2 = (const float*)d_in[7];
  const float* Wh2 = (const float*)d_in[8];
  const float* bi2 = (const float*)d_in[9];
  const float* bh2 = (const float*)d_in[10];
  const float* Wi1 = (const float*)d_in[11];
  const float* Wh1 = (const float*)d_in[12];
  const float* bi1 = (const float*)d_in[13];
  const float* bh1 = (const float*)d_in[14];
  const float* Wout = (const float*)d_in[15];
  const float* bout = (const float*)d_in[16];
  float* out = (float*)d_out;

  hipLaunchKernelGGL(mlstm_kernel, dim3(256), dim3(512), 0, stream,
                     x1, x2, x3, Wi3, Wh3, bi3, bh3, Wi2, Wh2, bi2, bh2,
                     Wi1, Wh1, bi1, bh1, Wout, bout, out);
}